// Round 4
// baseline (8565.432 us; speedup 1.0000x reference)
//
#include <hip/hip_runtime.h>
#include <hip/hip_bf16.h>

// Problem dims
#define T_STEPS 2048
#define BATCH   256
#define INW     64
#define H1      1280
#define H4D     320
#define H8D     160
#define G4      640   // 4*H8
#define ONUM    32

typedef __attribute__((ext_vector_type(8))) short short8;   // 8 x bf16
typedef __attribute__((ext_vector_type(4))) float floatx4;
typedef __hip_bfloat16 bf16;

__device__ __forceinline__ float b2f(bf16 v) { return __bfloat162float(v); }
__device__ __forceinline__ bf16  f2b(float v) { return __float2bfloat16(v); }
__device__ __forceinline__ float fsig(float x)  { return __fdividef(1.0f, 1.0f + __expf(-x)); }
__device__ __forceinline__ float ftanh(float x) { return __fdividef(2.0f, 1.0f + __expf(-2.0f * x)) - 1.0f; }

// ---------------- cast fp32 -> bf16 (vectorized x4) ----------------
struct bf16x4 { bf16 a, b, c, d; };
__global__ void cast_f32_bf16_v4(const float* __restrict__ s, bf16* __restrict__ d, int n4) {
  int i = blockIdx.x * blockDim.x + threadIdx.x;
  if (i >= n4) return;
  float4 v = reinterpret_cast<const float4*>(s)[i];
  bf16x4 o{f2b(v.x), f2b(v.y), f2b(v.z), f2b(v.w)};
  reinterpret_cast<bf16x4*>(d)[i] = o;
}

// ---------------- GEMM: C = act(A[M,K] @ W[N,K]^T + bias) ----------------
// 128x128 tile (m93 structure), 256 threads = 4 waves in 2x2 grid, each wave
// a 64x64 quadrant (4x4 MFMA tiles), BK=64. M % 128 == 0 assumed; N guarded.
// ACT: 1 = leaky_relu(0.01)+bias, bf16 out (Cb)
//      2 = gate-interleaved f32 out: Cf[row][ix*4+g] (col = g*160+ix), bias+bias2 folded
template <int ACT>
__global__ __launch_bounds__(256) void gemm128(
    const bf16* __restrict__ A, const bf16* __restrict__ W,
    const float* __restrict__ bias, const float* __restrict__ bias2,
    bf16* __restrict__ Cb, float* __restrict__ Cf, int M, int N, int K)
{
  __shared__ __align__(16) bf16 As[128][72];   // +8 pad: rows 16B-aligned, 2-way max alias
  __shared__ __align__(16) bf16 Ws[128][72];
  const int tid  = threadIdx.x;
  const int lane = tid & 63;
  const int wave = tid >> 6;
  const int mrow = lane & 15;
  const int quad = lane >> 4;
  const int bm = blockIdx.x * 128;
  const int bn = blockIdx.y * 128;
  const int wm = (wave >> 1) * 64;
  const int wn = (wave & 1) * 64;
  const int lr = tid >> 1;          // staging row 0..127
  const int ls = (tid & 1) * 32;    // staging k-segment 0 or 32

  const int wr = (bn + lr < N) ? (bn + lr) : (N - 1);  // clamp W rows (fc2 N=320)

  floatx4 acc[4][4] = {};

  for (int k0 = 0; k0 < K; k0 += 64) {
    short8 a[4], w[4];
#pragma unroll
    for (int i = 0; i < 4; ++i) {
      a[i] = *reinterpret_cast<const short8*>(&A[(size_t)(bm + lr) * K + k0 + ls + i * 8]);
      w[i] = *reinterpret_cast<const short8*>(&W[(size_t)wr * K + k0 + ls + i * 8]);
    }
    __syncthreads();
#pragma unroll
    for (int i = 0; i < 4; ++i) {
      *reinterpret_cast<short8*>(&As[lr][ls + i * 8]) = a[i];
      *reinterpret_cast<short8*>(&Ws[lr][ls + i * 8]) = w[i];
    }
    __syncthreads();
#pragma unroll
    for (int kk = 0; kk < 2; ++kk) {
      short8 af[4], wf[4];
#pragma unroll
      for (int i = 0; i < 4; ++i)
        af[i] = *reinterpret_cast<const short8*>(&As[wm + i * 16 + mrow][kk * 32 + quad * 8]);
#pragma unroll
      for (int j = 0; j < 4; ++j)
        wf[j] = *reinterpret_cast<const short8*>(&Ws[wn + j * 16 + mrow][kk * 32 + quad * 8]);
#pragma unroll
      for (int i = 0; i < 4; ++i)
#pragma unroll
        for (int j = 0; j < 4; ++j)
          acc[i][j] = __builtin_amdgcn_mfma_f32_16x16x32_bf16(af[i], wf[j], acc[i][j], 0, 0, 0);
    }
  }

#pragma unroll
  for (int j = 0; j < 4; ++j) {
    int col = bn + wn + j * 16 + mrow;
    if (col >= N) continue;
    float bv = (ACT == 2) ? (bias[col] + bias2[col]) : bias[col];
    int g = 0, ix = 0;
    if (ACT == 2) { g = col / 160; ix = col - g * 160; }
#pragma unroll
    for (int i = 0; i < 4; ++i) {
#pragma unroll
      for (int r = 0; r < 4; ++r) {
        int row = bm + wm + i * 16 + quad * 4 + r;
        float v = acc[i][j][r] + bv;
        if (ACT == 1) {
          v = (v > 0.0f) ? v : 0.01f * v;
          Cb[(size_t)row * N + col] = f2b(v);
        } else {
          Cf[(size_t)row * 640 + ix * 4 + g] = v;
        }
      }
    }
  }
}

// ---------------- recurrent kernel ----------------
// 16 blocks x 640 threads (10 waves), block b owns batch rows [16b,16b+16).
// Wave w owns ix columns [16w,16w+16) = Whh output tiles {w,10+w,20+w,30+w}:
// each lane's acc[4] holds ALL FOUR gates of its 4 (row,ix) cells ->
// elementwise fully in registers (c in VGPRs). h double-buffered in LDS,
// one barrier per step. gx register-double-buffered (prefetch t+1 at top of t).
// y_t = h_t @ W3^T computed at iteration t+1 reusing the af fragments.
__global__ __launch_bounds__(640, 1) void recur_kernel(
    const float* __restrict__ gx,     // [Tc*256][160][4] f32, biases folded
    const bf16* __restrict__ Whh,     // [640,160] bf16
    const bf16* __restrict__ W3w,     // [32,160]  bf16
    const float* __restrict__ b3,
    bf16* __restrict__ h_ws,          // [256,160] bf16 (persist across chunks)
    float* __restrict__ c_ws,         // [256,160] f32
    float* __restrict__ outp,         // out + chunk offset: [Tc*256*32]
    int Tc, int init)
{
  __shared__ __align__(16) bf16 hbuf[2][16][168];  // double-buffered h tile
  __shared__ __align__(16) bf16 w3s[32][168];
  const int tid  = threadIdx.x;
  const int lane = tid & 63;
  const int wave = tid >> 6;    // 0..9
  const int mrow = lane & 15;
  const int quad = lane >> 4;
  const int bbase = blockIdx.x * 16;
  const int ixg = wave * 16 + mrow;   // this lane's ix column

  // W_hh fragments in registers: 4 gates x 5 k-steps = 80 VGPRs/lane
  short8 whf[4][5];
#pragma unroll
  for (int g = 0; g < 4; ++g)
#pragma unroll
    for (int ks = 0; ks < 5; ++ks)
      whf[g][ks] = *reinterpret_cast<const short8*>(
          &Whh[(size_t)(g * 160 + ixg) * 160 + ks * 32 + quad * 8]);

  // W3 into LDS (read per-iter by waves 0,1)
  for (int e = tid; e < 32 * 160; e += 640) {
    int r = e / 160, cix = e - r * 160;
    w3s[r][cix] = W3w[e];
  }
  const float b3v = (wave < 2) ? b3[wave * 16 + mrow] : 0.0f;

  // c state in registers; h into hbuf[0]
  float c[4];
#pragma unroll
  for (int r = 0; r < 4; ++r)
    c[r] = init ? 0.0f : c_ws[(size_t)(bbase + quad * 4 + r) * 160 + ixg];
  for (int e = tid; e < 16 * 160; e += 640) {
    int r = e / 160, cix = e - r * 160;
    hbuf[0][r][cix] = init ? f2b(0.0f) : h_ws[(size_t)(bbase + r) * 160 + cix];
  }
  __syncthreads();

  const float4* __restrict__ gxp = reinterpret_cast<const float4*>(gx);
  size_t goff[4];
#pragma unroll
  for (int r = 0; r < 4; ++r)
    goff[r] = (size_t)(bbase + quad * 4 + r) * 160 + ixg;

  float4 gcur[4], gnext[4];
#pragma unroll
  for (int r = 0; r < 4; ++r) gcur[r] = gxp[goff[r]];   // t = 0

  for (int t = 0; t < Tc; ++t) {
    const int rb = t & 1, wb = rb ^ 1;

    // prefetch gx[t+1]: consumed next iteration; latency covered by full step
    if (t + 1 < Tc) {
      size_t tb = (size_t)(t + 1) * (256 * 160);
#pragma unroll
      for (int r = 0; r < 4; ++r) gnext[r] = gxp[tb + goff[r]];
    }

    // h fragments (A-operand) from current buffer
    short8 af[5];
#pragma unroll
    for (int ks = 0; ks < 5; ++ks)
      af[ks] = *reinterpret_cast<const short8*>(&hbuf[rb][mrow][ks * 32 + quad * 8]);

    // y for step t-1 (af == h_{t-1} fragments), waves 0,1
    if (wave < 2 && t > 0) {
      short8 w3f[5];
#pragma unroll
      for (int ks = 0; ks < 5; ++ks)
        w3f[ks] = *reinterpret_cast<const short8*>(&w3s[wave * 16 + mrow][ks * 32 + quad * 8]);
      floatx4 ya = {};
#pragma unroll
      for (int ks = 0; ks < 5; ++ks)
        ya = __builtin_amdgcn_mfma_f32_16x16x32_bf16(af[ks], w3f[ks], ya, 0, 0, 0);
      float* op = outp + ((size_t)(t - 1) * 256 + bbase) * 32 + wave * 16 + mrow;
#pragma unroll
      for (int r = 0; r < 4; ++r)
        op[(size_t)(quad * 4 + r) * 32] = ya[r] + b3v;
    }

    // hh MFMA: acc[g][r] = gate_g[row=quad*4+r][ix=ixg]
    floatx4 acc[4] = {};
#pragma unroll
    for (int ks = 0; ks < 5; ++ks)
#pragma unroll
      for (int g = 0; g < 4; ++g)
        acc[g] = __builtin_amdgcn_mfma_f32_16x16x32_bf16(af[ks], whf[g][ks], acc[g], 0, 0, 0);

    // LSTM cell, fully in registers (gcur loaded one step ahead)
#pragma unroll
    for (int r = 0; r < 4; ++r) {
      float xi = acc[0][r] + gcur[r].x;
      float xf = acc[1][r] + gcur[r].y;
      float xg = acc[2][r] + gcur[r].z;
      float xo = acc[3][r] + gcur[r].w;
      float iv = fsig(xi), fv = fsig(xf), gvv = ftanh(xg), ov = fsig(xo);
      float cv = fv * c[r] + iv * gvv;
      c[r] = cv;
      hbuf[wb][quad * 4 + r][ixg] = f2b(ov * ftanh(cv));
    }
#pragma unroll
    for (int r = 0; r < 4; ++r) gcur[r] = gnext[r];
    __syncthreads();
  }

  // final y for step Tc-1
  if (wave < 2) {
    const int rb = Tc & 1;
    short8 af[5], w3f[5];
#pragma unroll
    for (int ks = 0; ks < 5; ++ks) {
      af[ks]  = *reinterpret_cast<const short8*>(&hbuf[rb][mrow][ks * 32 + quad * 8]);
      w3f[ks] = *reinterpret_cast<const short8*>(&w3s[wave * 16 + mrow][ks * 32 + quad * 8]);
    }
    floatx4 ya = {};
#pragma unroll
    for (int ks = 0; ks < 5; ++ks)
      ya = __builtin_amdgcn_mfma_f32_16x16x32_bf16(af[ks], w3f[ks], ya, 0, 0, 0);
    float* op = outp + ((size_t)(Tc - 1) * 256 + bbase) * 32 + wave * 16 + mrow;
#pragma unroll
    for (int r = 0; r < 4; ++r)
      op[(size_t)(quad * 4 + r) * 32] = ya[r] + b3v;
  }

  // persist state
  for (int e = tid; e < 16 * 160; e += 640) {
    int r = e / 160, cix = e - r * 160;
    h_ws[(size_t)(bbase + r) * 160 + cix] = hbuf[Tc & 1][r][cix];
  }
#pragma unroll
  for (int r = 0; r < 4; ++r)
    c_ws[(size_t)(bbase + quad * 4 + r) * 160 + ixg] = c[r];
}

// ---------------- launch ----------------
extern "C" void kernel_launch(void* const* d_in, const int* in_sizes, int n_in,
                              void* d_out, int out_size, void* d_ws, size_t ws_size,
                              hipStream_t stream)
{
  const float* inp = (const float*)d_in[0];
  const float* W1  = (const float*)d_in[1];
  const float* b1  = (const float*)d_in[2];
  const float* W2  = (const float*)d_in[3];
  const float* b2  = (const float*)d_in[4];
  const float* Wih = (const float*)d_in[5];
  const float* Whh = (const float*)d_in[6];
  const float* bih = (const float*)d_in[7];
  const float* bhh = (const float*)d_in[8];
  const float* W3  = (const float*)d_in[9];
  const float* b3  = (const float*)d_in[10];
  float* out = (float*)d_out;

  char* ws = (char*)d_ws;
  size_t off = 0;
  auto alloc = [&](size_t bytes) -> char* {
    char* p = ws + off;
    off += (bytes + 255) & ~(size_t)255;
    return p;
  };

  bf16* inpb = (bf16*)alloc((size_t)T_STEPS * BATCH * INW * 2);
  bf16* w1b  = (bf16*)alloc((size_t)H1 * INW * 2);
  bf16* w2b  = (bf16*)alloc((size_t)H4D * H1 * 2);
  bf16* wihb = (bf16*)alloc((size_t)G4 * H4D * 2);
  bf16* whhb = (bf16*)alloc((size_t)G4 * H8D * 2);
  bf16* w3b  = (bf16*)alloc((size_t)ONUM * H8D * 2);
  bf16* h_ws = (bf16*)alloc((size_t)BATCH * H8D * 2);
  float* c_ws = (float*)alloc((size_t)BATCH * H8D * 4);
  size_t fixed = off;

  int Tc = 128;  // time chunk; shrink if workspace is small
  while (Tc > 16) {
    size_t Mc = (size_t)Tc * BATCH;
    size_t need = fixed
      + ((Mc * H1 * 2 + 255) & ~(size_t)255)
      + ((Mc * H4D * 2 + 255) & ~(size_t)255)
      + ((Mc * G4 * 4 + 255) & ~(size_t)255);   // gx is f32
    if (need <= ws_size) break;
    Tc >>= 1;
  }
  const size_t Mc = (size_t)Tc * BATCH;
  bf16*  x2 = (bf16*)alloc(Mc * H1 * 2);
  bf16*  x4 = (bf16*)alloc(Mc * H4D * 2);
  float* gx = (float*)alloc(Mc * G4 * 4);

  // casts (done every call; harness re-poisons ws before each timed launch)
  {
    int n4 = T_STEPS * BATCH * INW / 4;
    cast_f32_bf16_v4<<<(n4 + 255) / 256, 256, 0, stream>>>(inp, inpb, n4);
    n4 = H1 * INW / 4;
    cast_f32_bf16_v4<<<(n4 + 255) / 256, 256, 0, stream>>>(W1, w1b, n4);
    n4 = H4D * H1 / 4;
    cast_f32_bf16_v4<<<(n4 + 255) / 256, 256, 0, stream>>>(W2, w2b, n4);
    n4 = G4 * H4D / 4;
    cast_f32_bf16_v4<<<(n4 + 255) / 256, 256, 0, stream>>>(Wih, wihb, n4);
    n4 = G4 * H8D / 4;
    cast_f32_bf16_v4<<<(n4 + 255) / 256, 256, 0, stream>>>(Whh, whhb, n4);
    n4 = ONUM * H8D / 4;
    cast_f32_bf16_v4<<<(n4 + 255) / 256, 256, 0, stream>>>(W3, w3b, n4);
  }

  const int nchunks = T_STEPS / Tc;
  for (int ch = 0; ch < nchunks; ++ch) {
    const bf16* Ain = inpb + (size_t)ch * Mc * INW;
    gemm128<1><<<dim3((unsigned)(Mc / 128), H1 / 128), 256, 0, stream>>>(
        Ain, w1b, b1, nullptr, x2, nullptr, (int)Mc, H1, INW);
    gemm128<1><<<dim3((unsigned)(Mc / 128), (H4D + 127) / 128), 256, 0, stream>>>(
        x2, w2b, b2, nullptr, x4, nullptr, (int)Mc, H4D, H1);
    gemm128<2><<<dim3((unsigned)(Mc / 128), G4 / 128), 256, 0, stream>>>(
        x4, wihb, bih, bhh, nullptr, gx, (int)Mc, G4, H4D);
    recur_kernel<<<16, 640, 0, stream>>>(
        gx, whhb, w3b, b3, h_ws, c_ws,
        out + (size_t)ch * Tc * BATCH * ONUM, Tc, ch == 0 ? 1 : 0);
  }
}

// Round 5
// 4222.864 us; speedup vs baseline: 2.0283x; 2.0283x over previous
//
#include <hip/hip_runtime.h>
#include <hip/hip_bf16.h>

// Problem dims
#define T_STEPS 2048
#define BATCH   256
#define INW     64
#define H1      1280
#define H4D     320
#define H8D     160
#define G4      640   // 4*H8
#define ONUM    32

typedef __attribute__((ext_vector_type(8))) short short8;   // 8 x bf16
typedef __attribute__((ext_vector_type(4))) float floatx4;
typedef __hip_bfloat16 bf16;

__device__ __forceinline__ float b2f(bf16 v) { return __bfloat162float(v); }
__device__ __forceinline__ bf16  f2b(float v) { return __float2bfloat16(v); }
__device__ __forceinline__ float bfu(unsigned short u) { return __uint_as_float((unsigned)u << 16); }
__device__ __forceinline__ float fsig(float x)  { return __fdividef(1.0f, 1.0f + __expf(-x)); }
__device__ __forceinline__ float ftanh(float x) { return __fdividef(2.0f, 1.0f + __expf(-2.0f * x)) - 1.0f; }

// LDS-only barrier: drains ds ops, leaves global loads in flight (no vmcnt).
__device__ __forceinline__ void lds_barrier() {
  asm volatile("s_waitcnt lgkmcnt(0)\n\ts_barrier" ::: "memory");
}

// ---------------- cast fp32 -> bf16 (vectorized x4) ----------------
struct bf16x4 { bf16 a, b, c, d; };
__global__ void cast_f32_bf16_v4(const float* __restrict__ s, bf16* __restrict__ d, int n4) {
  int i = blockIdx.x * blockDim.x + threadIdx.x;
  if (i >= n4) return;
  float4 v = reinterpret_cast<const float4*>(s)[i];
  bf16x4 o{f2b(v.x), f2b(v.y), f2b(v.z), f2b(v.w)};
  reinterpret_cast<bf16x4*>(d)[i] = o;
}

// ---------------- GEMM: C = act(A[M,K] @ W[N,K]^T + bias) ----------------
// 128x128 tile, 256 threads = 4 waves in 2x2 grid, each wave a 64x64 quadrant
// (4x4 MFMA tiles), BK=64. M % 128 == 0 assumed; N guarded (fc2 N=320).
// ACT: 1 = leaky_relu(0.01)+bias, bf16 out
//      2 = gate-interleaved bf16 out: C[row][ix*4+g] (col = g*160+ix), bias+bias2 folded
template <int ACT>
__global__ __launch_bounds__(256) void gemm128(
    const bf16* __restrict__ A, const bf16* __restrict__ W,
    const float* __restrict__ bias, const float* __restrict__ bias2,
    bf16* __restrict__ Cb, int M, int N, int K)
{
  __shared__ __align__(16) bf16 As[128][72];   // +8 pad: rows 16B-aligned, 2-way max alias
  __shared__ __align__(16) bf16 Ws[128][72];
  const int tid  = threadIdx.x;
  const int lane = tid & 63;
  const int wave = tid >> 6;
  const int mrow = lane & 15;
  const int quad = lane >> 4;
  const int bm = blockIdx.x * 128;
  const int bn = blockIdx.y * 128;
  const int wm = (wave >> 1) * 64;
  const int wn = (wave & 1) * 64;
  const int lr = tid >> 1;          // staging row 0..127
  const int ls = (tid & 1) * 32;    // staging k-segment 0 or 32

  const int wr = (bn + lr < N) ? (bn + lr) : (N - 1);  // clamp W rows

  floatx4 acc[4][4] = {};

  for (int k0 = 0; k0 < K; k0 += 64) {
    short8 a[4], w[4];
#pragma unroll
    for (int i = 0; i < 4; ++i) {
      a[i] = *reinterpret_cast<const short8*>(&A[(size_t)(bm + lr) * K + k0 + ls + i * 8]);
      w[i] = *reinterpret_cast<const short8*>(&W[(size_t)wr * K + k0 + ls + i * 8]);
    }
    __syncthreads();
#pragma unroll
    for (int i = 0; i < 4; ++i) {
      *reinterpret_cast<short8*>(&As[lr][ls + i * 8]) = a[i];
      *reinterpret_cast<short8*>(&Ws[lr][ls + i * 8]) = w[i];
    }
    __syncthreads();
#pragma unroll
    for (int kk = 0; kk < 2; ++kk) {
      short8 af[4], wf[4];
#pragma unroll
      for (int i = 0; i < 4; ++i)
        af[i] = *reinterpret_cast<const short8*>(&As[wm + i * 16 + mrow][kk * 32 + quad * 8]);
#pragma unroll
      for (int j = 0; j < 4; ++j)
        wf[j] = *reinterpret_cast<const short8*>(&Ws[wn + j * 16 + mrow][kk * 32 + quad * 8]);
#pragma unroll
      for (int i = 0; i < 4; ++i)
#pragma unroll
        for (int j = 0; j < 4; ++j)
          acc[i][j] = __builtin_amdgcn_mfma_f32_16x16x32_bf16(af[i], wf[j], acc[i][j], 0, 0, 0);
    }
  }

#pragma unroll
  for (int j = 0; j < 4; ++j) {
    int col = bn + wn + j * 16 + mrow;
    if (col >= N) continue;
    float bv = (ACT == 2) ? (bias[col] + bias2[col]) : bias[col];
    int g = 0, ix = 0;
    if (ACT == 2) { g = col / 160; ix = col - g * 160; }
#pragma unroll
    for (int i = 0; i < 4; ++i) {
#pragma unroll
      for (int r = 0; r < 4; ++r) {
        int row = bm + wm + i * 16 + quad * 4 + r;
        float v = acc[i][j][r] + bv;
        if (ACT == 1) {
          v = (v > 0.0f) ? v : 0.01f * v;
          Cb[(size_t)row * N + col] = f2b(v);
        } else {
          Cb[(size_t)row * 640 + ix * 4 + g] = f2b(v);
        }
      }
    }
  }
}

// ---------------- recurrent kernel ----------------
// 64 blocks x 640 threads (10 waves); block b owns batch rows [4b, 4b+4),
// mapped to MFMA M-slots {0,4,8,12} so lane (wave w, quad q, mrow m) owns
// exactly ONE cell: (row 4b+q, ix = 16w+m) at acc reg r=0 -> elementwise is
// 10 trans/lane/step, no divergence. Wave w owns Whh output tiles
// {w,10+w,20+w,30+w} so acc[4] = all four gates of the cell.
// h double-buffered in LDS; in-loop barrier is lgkm-only (global loads stay
// in flight across it) -> gx prefetch (distance 1) genuinely overlaps a step.
__global__ __launch_bounds__(640, 1) void recur_kernel(
    const bf16* __restrict__ gx,      // [Tc*256][160][4] bf16, biases folded
    const bf16* __restrict__ Whh,     // [640,160] bf16
    const bf16* __restrict__ W3w,     // [32,160]  bf16
    const float* __restrict__ b3,
    bf16* __restrict__ h_ws,          // [256,160] bf16 (persist across chunks)
    float* __restrict__ c_ws,         // [256,160] f32
    float* __restrict__ outp,         // out + chunk offset: [Tc*256*32]
    int Tc, int init)
{
  __shared__ __align__(16) bf16 hbuf[2][16][168];  // double-buffered h tile
  __shared__ __align__(16) bf16 w3s[32][168];
  const int tid  = threadIdx.x;
  const int lane = tid & 63;
  const int wave = tid >> 6;    // 0..9
  const int mrow = lane & 15;
  const int quad = lane >> 4;   // 0..3 == local batch row
  const int bbase = blockIdx.x * 4;
  const int ixg = wave * 16 + mrow;   // this lane's ix column

  // W_hh fragments in registers: 4 gates x 5 k-steps = 80 VGPRs/lane
  short8 whf[4][5];
#pragma unroll
  for (int g = 0; g < 4; ++g)
#pragma unroll
    for (int ks = 0; ks < 5; ++ks)
      whf[g][ks] = *reinterpret_cast<const short8*>(
          &Whh[(size_t)(g * 160 + ixg) * 160 + ks * 32 + quad * 8]);

  // W3 into LDS (read per-iter by waves 0,1)
  for (int e = tid; e < 32 * 160; e += 640) {
    int r = e / 160, cix = e - r * 160;
    w3s[r][cix] = W3w[e];
  }
  const float b3v = (wave < 2) ? b3[wave * 16 + mrow] : 0.0f;

  // zero both h buffers (padding M-slots must be clean), then fill real slots
  for (int e = tid; e < 2 * 16 * 168; e += 640)
    reinterpret_cast<bf16*>(hbuf)[e] = f2b(0.0f);
  __syncthreads();
  {
    int r = tid / 160, cix = tid - r * 160;   // 640 threads == 4*160 elems
    hbuf[0][r * 4][cix] = init ? f2b(0.0f) : h_ws[(size_t)(bbase + r) * 160 + cix];
  }
  float c0 = init ? 0.0f : c_ws[(size_t)(bbase + quad) * 160 + ixg];
  __syncthreads();

  const uint2* __restrict__ gxp = reinterpret_cast<const uint2*>(gx);
  const size_t goff = (size_t)(bbase + quad) * 160 + ixg;

  uint2 gcur = gxp[goff], gnext = gcur;

  for (int t = 0; t < Tc; ++t) {
    const int rb = t & 1, wb = rb ^ 1;

    // prefetch gx[t+1]; stays in flight across the lgkm-only barrier
    if (t + 1 < Tc) gnext = gxp[(size_t)(t + 1) * (256 * 160) + goff];

    // h fragments (A-operand) from current buffer
    short8 af[5];
#pragma unroll
    for (int ks = 0; ks < 5; ++ks)
      af[ks] = *reinterpret_cast<const short8*>(&hbuf[rb][mrow][ks * 32 + quad * 8]);

    // y for step t-1 (af == h_{t-1} fragments), waves 0,1, reg 0 only
    if (wave < 2 && t > 0) {
      short8 w3f[5];
#pragma unroll
      for (int ks = 0; ks < 5; ++ks)
        w3f[ks] = *reinterpret_cast<const short8*>(&w3s[wave * 16 + mrow][ks * 32 + quad * 8]);
      floatx4 ya = {};
#pragma unroll
      for (int ks = 0; ks < 5; ++ks)
        ya = __builtin_amdgcn_mfma_f32_16x16x32_bf16(af[ks], w3f[ks], ya, 0, 0, 0);
      outp[((size_t)(t - 1) * 256 + bbase + quad) * 32 + wave * 16 + mrow] = ya[0] + b3v;
    }

    // hh MFMA: acc[g][0] = gate_g[row=quad][ix=ixg]
    floatx4 acc[4] = {};
#pragma unroll
    for (int ks = 0; ks < 5; ++ks)
#pragma unroll
      for (int g = 0; g < 4; ++g)
        acc[g] = __builtin_amdgcn_mfma_f32_16x16x32_bf16(af[ks], whf[g][ks], acc[g], 0, 0, 0);

    // LSTM cell: one cell per lane, in registers
    {
      union { uint2 u; unsigned short s[4]; } q;
      q.u = gcur;
      float xi = acc[0][0] + bfu(q.s[0]);
      float xf = acc[1][0] + bfu(q.s[1]);
      float xg = acc[2][0] + bfu(q.s[2]);
      float xo = acc[3][0] + bfu(q.s[3]);
      float iv = fsig(xi), fv = fsig(xf), gvv = ftanh(xg), ov = fsig(xo);
      c0 = fv * c0 + iv * gvv;
      hbuf[wb][quad * 4][ixg] = f2b(ov * ftanh(c0));
    }
    gcur = gnext;
    lds_barrier();
  }

  // final y for step Tc-1
  if (wave < 2) {
    const int rb = Tc & 1;
    short8 af[5], w3f[5];
#pragma unroll
    for (int ks = 0; ks < 5; ++ks) {
      af[ks]  = *reinterpret_cast<const short8*>(&hbuf[rb][mrow][ks * 32 + quad * 8]);
      w3f[ks] = *reinterpret_cast<const short8*>(&w3s[wave * 16 + mrow][ks * 32 + quad * 8]);
    }
    floatx4 ya = {};
#pragma unroll
    for (int ks = 0; ks < 5; ++ks)
      ya = __builtin_amdgcn_mfma_f32_16x16x32_bf16(af[ks], w3f[ks], ya, 0, 0, 0);
    outp[((size_t)(Tc - 1) * 256 + bbase + quad) * 32 + wave * 16 + mrow] = ya[0] + b3v;
  }

  // persist state
  {
    int r = tid / 160, cix = tid - r * 160;
    h_ws[(size_t)(bbase + r) * 160 + cix] = hbuf[Tc & 1][r * 4][cix];
  }
  c_ws[(size_t)(bbase + quad) * 160 + ixg] = c0;
}

// ---------------- launch ----------------
extern "C" void kernel_launch(void* const* d_in, const int* in_sizes, int n_in,
                              void* d_out, int out_size, void* d_ws, size_t ws_size,
                              hipStream_t stream)
{
  const float* inp = (const float*)d_in[0];
  const float* W1  = (const float*)d_in[1];
  const float* b1  = (const float*)d_in[2];
  const float* W2  = (const float*)d_in[3];
  const float* b2  = (const float*)d_in[4];
  const float* Wih = (const float*)d_in[5];
  const float* Whh = (const float*)d_in[6];
  const float* bih = (const float*)d_in[7];
  const float* bhh = (const float*)d_in[8];
  const float* W3  = (const float*)d_in[9];
  const float* b3  = (const float*)d_in[10];
  float* out = (float*)d_out;

  char* ws = (char*)d_ws;
  size_t off = 0;
  auto alloc = [&](size_t bytes) -> char* {
    char* p = ws + off;
    off += (bytes + 255) & ~(size_t)255;
    return p;
  };

  bf16* inpb = (bf16*)alloc((size_t)T_STEPS * BATCH * INW * 2);
  bf16* w1b  = (bf16*)alloc((size_t)H1 * INW * 2);
  bf16* w2b  = (bf16*)alloc((size_t)H4D * H1 * 2);
  bf16* wihb = (bf16*)alloc((size_t)G4 * H4D * 2);
  bf16* whhb = (bf16*)alloc((size_t)G4 * H8D * 2);
  bf16* w3b  = (bf16*)alloc((size_t)ONUM * H8D * 2);
  bf16* h_ws = (bf16*)alloc((size_t)BATCH * H8D * 2);
  float* c_ws = (float*)alloc((size_t)BATCH * H8D * 4);
  size_t fixed = off;

  int Tc = 128;  // time chunk; shrink if workspace is small
  while (Tc > 16) {
    size_t Mc = (size_t)Tc * BATCH;
    size_t need = fixed
      + ((Mc * H1 * 2 + 255) & ~(size_t)255)
      + ((Mc * H4D * 2 + 255) & ~(size_t)255)
      + ((Mc * G4 * 2 + 255) & ~(size_t)255);   // gx bf16
    if (need <= ws_size) break;
    Tc >>= 1;
  }
  const size_t Mc = (size_t)Tc * BATCH;
  bf16* x2 = (bf16*)alloc(Mc * H1 * 2);
  bf16* x4 = (bf16*)alloc(Mc * H4D * 2);
  bf16* gx = (bf16*)alloc(Mc * G4 * 2);

  // casts (done every call; harness re-poisons ws before each timed launch)
  {
    int n4 = T_STEPS * BATCH * INW / 4;
    cast_f32_bf16_v4<<<(n4 + 255) / 256, 256, 0, stream>>>(inp, inpb, n4);
    n4 = H1 * INW / 4;
    cast_f32_bf16_v4<<<(n4 + 255) / 256, 256, 0, stream>>>(W1, w1b, n4);
    n4 = H4D * H1 / 4;
    cast_f32_bf16_v4<<<(n4 + 255) / 256, 256, 0, stream>>>(W2, w2b, n4);
    n4 = G4 * H4D / 4;
    cast_f32_bf16_v4<<<(n4 + 255) / 256, 256, 0, stream>>>(Wih, wihb, n4);
    n4 = G4 * H8D / 4;
    cast_f32_bf16_v4<<<(n4 + 255) / 256, 256, 0, stream>>>(Whh, whhb, n4);
    n4 = ONUM * H8D / 4;
    cast_f32_bf16_v4<<<(n4 + 255) / 256, 256, 0, stream>>>(W3, w3b, n4);
  }

  const int nchunks = T_STEPS / Tc;
  for (int ch = 0; ch < nchunks; ++ch) {
    const bf16* Ain = inpb + (size_t)ch * Mc * INW;
    gemm128<1><<<dim3((unsigned)(Mc / 128), H1 / 128), 256, 0, stream>>>(
        Ain, w1b, b1, nullptr, x2, (int)Mc, H1, INW);
    gemm128<1><<<dim3((unsigned)(Mc / 128), (H4D + 127) / 128), 256, 0, stream>>>(
        x2, w2b, b2, nullptr, x4, (int)Mc, H4D, H1);
    gemm128<2><<<dim3((unsigned)(Mc / 128), G4 / 128), 256, 0, stream>>>(
        x4, wihb, bih, bhh, gx, (int)Mc, G4, H4D);
    recur_kernel<<<64, 640, 0, stream>>>(
        gx, whhb, w3b, b3, h_ws, c_ws,
        out + (size_t)ch * Tc * BATCH * ONUM, Tc, ch == 0 ? 1 : 0);
  }
}

// Round 6
// 2985.929 us; speedup vs baseline: 2.8686x; 1.4143x over previous
//
#include <hip/hip_runtime.h>
#include <hip/hip_bf16.h>

// Problem dims
#define T_STEPS 2048
#define BATCH   256
#define INW     64
#define H1      1280
#define H4D     320
#define H8D     160
#define G4      640   // 4*H8
#define ONUM    32

typedef __attribute__((ext_vector_type(8))) short short8;   // 8 x bf16
typedef __attribute__((ext_vector_type(4))) float floatx4;
typedef __hip_bfloat16 bf16;

__device__ __forceinline__ float b2f(bf16 v) { return __bfloat162float(v); }
__device__ __forceinline__ bf16  f2b(float v) { return __float2bfloat16(v); }
__device__ __forceinline__ float bfu(unsigned short u) { return __uint_as_float((unsigned)u << 16); }
__device__ __forceinline__ float fsig(float x)  { return __fdividef(1.0f, 1.0f + __expf(-x)); }
__device__ __forceinline__ float ftanh(float x) { return __fdividef(2.0f, 1.0f + __expf(-2.0f * x)) - 1.0f; }

// LDS-only barrier: drains ds ops, leaves global loads in flight (no vmcnt).
__device__ __forceinline__ void lds_barrier() {
  asm volatile("s_waitcnt lgkmcnt(0)\n\ts_barrier" ::: "memory");
}

// ---------------- cast fp32 -> bf16 (vectorized x4) ----------------
struct bf16x4 { bf16 a, b, c, d; };
__global__ void cast_f32_bf16_v4(const float* __restrict__ s, bf16* __restrict__ d, int n4) {
  int i = blockIdx.x * blockDim.x + threadIdx.x;
  if (i >= n4) return;
  float4 v = reinterpret_cast<const float4*>(s)[i];
  bf16x4 o{f2b(v.x), f2b(v.y), f2b(v.z), f2b(v.w)};
  reinterpret_cast<bf16x4*>(d)[i] = o;
}

// Shared scratch: max(gemm 128x72 + 160x72 bf16 = 41472 B, recur 21504 B)
#define SMEM_BYTES 41472

// ---------------- GEMM tile: 128x160, 640 threads (2x5 wave grid) ----------
// C = act(A[M,K] @ W[N,K]^T + bias). N % 160 == 0, M % 128 == 0, K % 64 == 0.
// ACT 1: leaky_relu + bias, row-major out. ACT 2: gate-interleave out
// C[row][ix*4+g] for col = g*160+ix, bias+bias2 folded.
__device__ void gemm_tile(char* smem, int tid, int mt, int nt,
                          const bf16* __restrict__ A, const bf16* __restrict__ W,
                          const float* __restrict__ bias, const float* __restrict__ bias2,
                          bf16* __restrict__ C, int N, int K, int ACT)
{
  bf16 (*As)[72] = reinterpret_cast<bf16 (*)[72]>(smem);            // 128 rows
  bf16 (*Ws)[72] = reinterpret_cast<bf16 (*)[72]>(smem + 128 * 72 * 2);  // 160 rows
  const int lane = tid & 63;
  const int wave = tid >> 6;            // 0..9
  const int mrow = lane & 15;
  const int quad = lane >> 4;
  const int wm = (wave >= 5) ? 64 : 0;
  const int wn = (wave - (wave >= 5 ? 5 : 0)) * 32;
  const int bm = mt * 128;
  const int bn = nt * 160;

  floatx4 acc[4][2] = {};

  const int va0 = tid, va1 = tid + 640;       // A vectors: 1024 total
  const int vw0 = tid, vw1 = tid + 640;       // W vectors: 1280 total

  for (int k0 = 0; k0 < K; k0 += 64) {
    short8 a0, a1, w0, w1;
    a0 = *reinterpret_cast<const short8*>(&A[(size_t)(bm + (va0 >> 3)) * K + k0 + (va0 & 7) * 8]);
    if (va1 < 1024)
      a1 = *reinterpret_cast<const short8*>(&A[(size_t)(bm + (va1 >> 3)) * K + k0 + (va1 & 7) * 8]);
    w0 = *reinterpret_cast<const short8*>(&W[(size_t)(bn + (vw0 >> 3)) * K + k0 + (vw0 & 7) * 8]);
    w1 = *reinterpret_cast<const short8*>(&W[(size_t)(bn + (vw1 >> 3)) * K + k0 + (vw1 & 7) * 8]);
    __syncthreads();
    *reinterpret_cast<short8*>(&As[va0 >> 3][(va0 & 7) * 8]) = a0;
    if (va1 < 1024)
      *reinterpret_cast<short8*>(&As[va1 >> 3][(va1 & 7) * 8]) = a1;
    *reinterpret_cast<short8*>(&Ws[vw0 >> 3][(vw0 & 7) * 8]) = w0;
    *reinterpret_cast<short8*>(&Ws[vw1 >> 3][(vw1 & 7) * 8]) = w1;
    __syncthreads();
#pragma unroll
    for (int kk = 0; kk < 2; ++kk) {
      short8 af[4], wf[2];
#pragma unroll
      for (int i = 0; i < 4; ++i)
        af[i] = *reinterpret_cast<const short8*>(&As[wm + i * 16 + mrow][kk * 32 + quad * 8]);
#pragma unroll
      for (int j = 0; j < 2; ++j)
        wf[j] = *reinterpret_cast<const short8*>(&Ws[wn + j * 16 + mrow][kk * 32 + quad * 8]);
#pragma unroll
      for (int i = 0; i < 4; ++i)
#pragma unroll
        for (int j = 0; j < 2; ++j)
          acc[i][j] = __builtin_amdgcn_mfma_f32_16x16x32_bf16(af[i], wf[j], acc[i][j], 0, 0, 0);
    }
  }

#pragma unroll
  for (int j = 0; j < 2; ++j) {
    int col = bn + wn + j * 16 + mrow;
    float bv = (ACT == 2) ? (bias[col] + bias2[col]) : bias[col];
    int g = 0, ix = 0;
    if (ACT == 2) { g = col / 160; ix = col - g * 160; }
#pragma unroll
    for (int i = 0; i < 4; ++i) {
#pragma unroll
      for (int r = 0; r < 4; ++r) {
        int row = bm + wm + i * 16 + quad * 4 + r;
        float v = acc[i][j][r] + bv;
        if (ACT == 1) {
          v = (v > 0.0f) ? v : 0.01f * v;
          C[(size_t)row * N + col] = f2b(v);
        } else {
          C[(size_t)row * 640 + ix * 4 + g] = f2b(v);
        }
      }
    }
  }
}

// ---------------- recur path (one block = 4 batch rows) ----------------
// See R5: lane (wave w, quad q, mrow m) owns cell (row 4b+q -> M-slot 4q,
// ix = 16w+m); acc[4] = all four gates; lgkm-only in-loop barrier keeps gx
// prefetch in flight across steps.
__device__ void recur_path(char* smem, int tid, int bid,
    const bf16* __restrict__ gx, const bf16* __restrict__ Whh,
    const bf16* __restrict__ W3w, const float* __restrict__ b3,
    bf16* __restrict__ h_ws, float* __restrict__ c_ws,
    float* __restrict__ outp, int Tc, int init)
{
  bf16 (*hbuf)[16][168] = reinterpret_cast<bf16 (*)[16][168]>(smem);     // 2 bufs
  bf16 (*w3s)[168] = reinterpret_cast<bf16 (*)[168]>(smem + 10752);      // 32 rows
  const int lane = tid & 63;
  const int wave = tid >> 6;
  const int mrow = lane & 15;
  const int quad = lane >> 4;
  const int bbase = bid * 4;
  const int ixg = wave * 16 + mrow;

  short8 whf[4][5];
#pragma unroll
  for (int g = 0; g < 4; ++g)
#pragma unroll
    for (int ks = 0; ks < 5; ++ks)
      whf[g][ks] = *reinterpret_cast<const short8*>(
          &Whh[(size_t)(g * 160 + ixg) * 160 + ks * 32 + quad * 8]);

  for (int e = tid; e < 32 * 160; e += 640) {
    int r = e / 160, cix = e - r * 160;
    w3s[r][cix] = W3w[e];
  }
  const float b3v = (wave < 2) ? b3[wave * 16 + mrow] : 0.0f;

  for (int e = tid; e < 2 * 16 * 168; e += 640)
    reinterpret_cast<bf16*>(hbuf)[e] = f2b(0.0f);
  __syncthreads();
  {
    int r = tid / 160, cix = tid - r * 160;
    hbuf[0][r * 4][cix] = init ? f2b(0.0f) : h_ws[(size_t)(bbase + r) * 160 + cix];
  }
  float c0 = init ? 0.0f : c_ws[(size_t)(bbase + quad) * 160 + ixg];
  __syncthreads();

  const uint2* __restrict__ gxp = reinterpret_cast<const uint2*>(gx);
  const size_t goff = (size_t)(bbase + quad) * 160 + ixg;
  uint2 gcur = gxp[goff], gnext = gcur;

  for (int t = 0; t < Tc; ++t) {
    const int rb = t & 1, wb = rb ^ 1;
    if (t + 1 < Tc) gnext = gxp[(size_t)(t + 1) * (256 * 160) + goff];

    short8 af[5];
#pragma unroll
    for (int ks = 0; ks < 5; ++ks)
      af[ks] = *reinterpret_cast<const short8*>(&hbuf[rb][mrow][ks * 32 + quad * 8]);

    if (wave < 2 && t > 0) {
      short8 w3f[5];
#pragma unroll
      for (int ks = 0; ks < 5; ++ks)
        w3f[ks] = *reinterpret_cast<const short8*>(&w3s[wave * 16 + mrow][ks * 32 + quad * 8]);
      floatx4 ya = {};
#pragma unroll
      for (int ks = 0; ks < 5; ++ks)
        ya = __builtin_amdgcn_mfma_f32_16x16x32_bf16(af[ks], w3f[ks], ya, 0, 0, 0);
      outp[((size_t)(t - 1) * 256 + bbase + quad) * 32 + wave * 16 + mrow] = ya[0] + b3v;
    }

    floatx4 acc[4] = {};
#pragma unroll
    for (int ks = 0; ks < 5; ++ks)
#pragma unroll
      for (int g = 0; g < 4; ++g)
        acc[g] = __builtin_amdgcn_mfma_f32_16x16x32_bf16(af[ks], whf[g][ks], acc[g], 0, 0, 0);

    {
      union { uint2 u; unsigned short s[4]; } q;
      q.u = gcur;
      float xi = acc[0][0] + bfu(q.s[0]);
      float xf = acc[1][0] + bfu(q.s[1]);
      float xg = acc[2][0] + bfu(q.s[2]);
      float xo = acc[3][0] + bfu(q.s[3]);
      float iv = fsig(xi), fv = fsig(xf), gvv = ftanh(xg), ov = fsig(xo);
      c0 = fv * c0 + iv * gvv;
      hbuf[wb][quad * 4][ixg] = f2b(ov * ftanh(c0));
    }
    gcur = gnext;
    lds_barrier();
  }

  if (wave < 2) {
    const int rb = Tc & 1;
    short8 af[5], w3f[5];
#pragma unroll
    for (int ks = 0; ks < 5; ++ks) {
      af[ks]  = *reinterpret_cast<const short8*>(&hbuf[rb][mrow][ks * 32 + quad * 8]);
      w3f[ks] = *reinterpret_cast<const short8*>(&w3s[wave * 16 + mrow][ks * 32 + quad * 8]);
    }
    floatx4 ya = {};
#pragma unroll
    for (int ks = 0; ks < 5; ++ks)
      ya = __builtin_amdgcn_mfma_f32_16x16x32_bf16(af[ks], w3f[ks], ya, 0, 0, 0);
    outp[((size_t)(Tc - 1) * 256 + bbase + quad) * 32 + wave * 16 + mrow] = ya[0] + b3v;
  }

  {
    int r = tid / 160, cix = tid - r * 160;
    h_ws[(size_t)(bbase + r) * 160 + cix] = hbuf[Tc & 1][r * 4][cix];
  }
  c_ws[(size_t)(bbase + quad) * 160 + ixg] = c0;
}

// ---------------- fused pipeline step ----------------
// blocks 0..63: recur(chunk L-3). Then nb1 blocks fc1(L), nb2 fc2(L-1),
// nb3 ih(L-2). All cross-stage dependencies are across launch boundaries.
__global__ __launch_bounds__(640, 1) void fused_step(
    int has_recur, const bf16* gxr, const bf16* Whh, const bf16* W3w,
    const float* b3, bf16* h_ws, float* c_ws, float* outp, int Tc, int init,
    int nb1, const bf16* A1, const bf16* W1w, const float* b1v, bf16* C1,
    int nb2, const bf16* A2, const bf16* W2w, const float* b2v, bf16* C2,
    int nb3, const bf16* A3, const bf16* Wiw, const float* bihv, const float* bhhv, bf16* C3,
    int nM)
{
  __shared__ __align__(16) char smem[SMEM_BYTES];
  const int tid = threadIdx.x;
  if (blockIdx.x < 64) {
    if (has_recur)
      recur_path(smem, tid, blockIdx.x, gxr, Whh, W3w, b3, h_ws, c_ws, outp, Tc, init);
    return;
  }
  int gb = blockIdx.x - 64;
  if (gb < nb1) {
    gemm_tile(smem, tid, gb % nM, gb / nM, A1, W1w, b1v, nullptr, C1, H1, INW, 1);
    return;
  }
  gb -= nb1;
  if (gb < nb2) {
    gemm_tile(smem, tid, gb % nM, gb / nM, A2, W2w, b2v, nullptr, C2, H4D, H1, 1);
    return;
  }
  gb -= nb2;
  gemm_tile(smem, tid, gb % nM, gb / nM, A3, Wiw, bihv, bhhv, C3, G4, H4D, 2);
}

// ---------------- launch ----------------
extern "C" void kernel_launch(void* const* d_in, const int* in_sizes, int n_in,
                              void* d_out, int out_size, void* d_ws, size_t ws_size,
                              hipStream_t stream)
{
  const float* inp = (const float*)d_in[0];
  const float* W1  = (const float*)d_in[1];
  const float* b1  = (const float*)d_in[2];
  const float* W2  = (const float*)d_in[3];
  const float* b2  = (const float*)d_in[4];
  const float* Wih = (const float*)d_in[5];
  const float* Whh = (const float*)d_in[6];
  const float* bih = (const float*)d_in[7];
  const float* bhh = (const float*)d_in[8];
  const float* W3  = (const float*)d_in[9];
  const float* b3  = (const float*)d_in[10];
  float* out = (float*)d_out;

  char* ws = (char*)d_ws;
  size_t off = 0;
  auto alloc = [&](size_t bytes) -> char* {
    char* p = ws + off;
    off += (bytes + 255) & ~(size_t)255;
    return p;
  };

  bf16* inpb = (bf16*)alloc((size_t)T_STEPS * BATCH * INW * 2);
  bf16* w1b  = (bf16*)alloc((size_t)H1 * INW * 2);
  bf16* w2b  = (bf16*)alloc((size_t)H4D * H1 * 2);
  bf16* wihb = (bf16*)alloc((size_t)G4 * H4D * 2);
  bf16* whhb = (bf16*)alloc((size_t)G4 * H8D * 2);
  bf16* w3b  = (bf16*)alloc((size_t)ONUM * H8D * 2);
  bf16* h_ws = (bf16*)alloc((size_t)BATCH * H8D * 2);
  float* c_ws = (float*)alloc((size_t)BATCH * H8D * 4);
  size_t fixed = off;

  // time chunk; double-buffered pipeline stages must fit the workspace
  int Tc = 128;
  while (Tc > 16) {
    size_t Mc = (size_t)Tc * BATCH;
    size_t need = fixed
      + 2 * ((Mc * H1 * 2 + 255) & ~(size_t)255)
      + 2 * ((Mc * H4D * 2 + 255) & ~(size_t)255)
      + 2 * ((Mc * G4 * 2 + 255) & ~(size_t)255);
    if (need <= ws_size) break;
    Tc >>= 1;
  }
  const size_t Mc = (size_t)Tc * BATCH;
  bf16* x2b[2], *x4b[2], *gxb[2];
  for (int i = 0; i < 2; ++i) x2b[i] = (bf16*)alloc(Mc * H1 * 2);
  for (int i = 0; i < 2; ++i) x4b[i] = (bf16*)alloc(Mc * H4D * 2);
  for (int i = 0; i < 2; ++i) gxb[i] = (bf16*)alloc(Mc * G4 * 2);

  // casts (every call; harness re-poisons ws before each timed launch)
  {
    int n4 = T_STEPS * BATCH * INW / 4;
    cast_f32_bf16_v4<<<(n4 + 255) / 256, 256, 0, stream>>>(inp, inpb, n4);
    n4 = H1 * INW / 4;
    cast_f32_bf16_v4<<<(n4 + 255) / 256, 256, 0, stream>>>(W1, w1b, n4);
    n4 = H4D * H1 / 4;
    cast_f32_bf16_v4<<<(n4 + 255) / 256, 256, 0, stream>>>(W2, w2b, n4);
    n4 = G4 * H4D / 4;
    cast_f32_bf16_v4<<<(n4 + 255) / 256, 256, 0, stream>>>(Wih, wihb, n4);
    n4 = G4 * H8D / 4;
    cast_f32_bf16_v4<<<(n4 + 255) / 256, 256, 0, stream>>>(Whh, whhb, n4);
    n4 = ONUM * H8D / 4;
    cast_f32_bf16_v4<<<(n4 + 255) / 256, 256, 0, stream>>>(W3, w3b, n4);
  }

  const int nch = T_STEPS / Tc;
  const int nM = (int)(Mc / 128);

  // Pipeline: launch L runs recur(L-3), fc1(L), fc2(L-1), ih(L-2)
  for (int L = 0; L < nch + 3; ++L) {
    const int cr = L - 3, c1 = L, c2 = L - 1, c3 = L - 2;
    const int nb1 = (c1 >= 0 && c1 < nch) ? nM * (H1 / 160) : 0;
    const int nb2 = (c2 >= 0 && c2 < nch) ? nM * (H4D / 160) : 0;
    const int nb3 = (c3 >= 0 && c3 < nch) ? nM * (G4 / 160) : 0;
    const int hasr = (cr >= 0 && cr < nch) ? 1 : 0;

    const bf16* gxr = gxb[hasr ? (cr & 1) : 0];
    float* outp = hasr ? (out + (size_t)cr * Tc * BATCH * ONUM) : out;
    const bf16* A1 = nb1 ? (inpb + (size_t)c1 * Mc * INW) : inpb;
    bf16* C1 = x2b[nb1 ? (c1 & 1) : 0];
    const bf16* A2 = x2b[nb2 ? (c2 & 1) : 0];
    bf16* C2 = x4b[nb2 ? (c2 & 1) : 0];
    const bf16* A3 = x4b[nb3 ? (c3 & 1) : 0];
    bf16* C3 = gxb[nb3 ? (c3 & 1) : 0];

    fused_step<<<64 + nb1 + nb2 + nb3, 640, 0, stream>>>(
        hasr, gxr, whhb, w3b, b3, h_ws, c_ws, outp, Tc, (cr == 0) ? 1 : 0,
        nb1, A1, w1b, b1, C1,
        nb2, A2, w2b, b2, C2,
        nb3, A3, wihb, bih, bhh, C3,
        nM);
  }
}